// Round 1
// baseline (300.786 us; speedup 1.0000x reference)
//
#include <hip/hip_runtime.h>
#include <hip/hip_bf16.h>

#define DEVFN __device__ __forceinline__

typedef __attribute__((ext_vector_type(4))) float  f32x4;
typedef __attribute__((ext_vector_type(4))) int    i32x4;
typedef __attribute__((ext_vector_type(8))) short  s16x8;

static constexpr int Bb = 2, Ss = 512, Kd = 4096, Nd = 16384;
static constexpr int Md = Bb * Ss;           // 1024

static constexpr int BM = 128, BN = 128, BK = 64;

// ---------- helpers ----------

DEVFN unsigned short f32_to_bf16_rne(float f) {
    unsigned u = __float_as_uint(f);
    unsigned r = u + 0x7FFFu + ((u >> 16) & 1u);
    return (unsigned short)(r >> 16);
}

// exact for |v| <= 255 (int8 range): truncation == exact conversion
DEVFN unsigned short i32_to_bf16_exact(int v) {
    return (unsigned short)(__float_as_uint((float)v) >> 16);
}

template <typename T>
DEVFN void gload_lds16(const T* g, T* l) {
    __builtin_amdgcn_global_load_lds(
        (const __attribute__((address_space(1))) void*)g,
        (__attribute__((address_space(3))) void*)l,
        16, 0, 0);
}

// ---------- conversion kernels ----------

__global__ __launch_bounds__(256) void convert_w_kernel(
    const int* __restrict__ wq, unsigned short* __restrict__ wb) {
    const int ngroups = (Nd / 8) * Kd;      // 8,388,608 groups of 8
    int g = blockIdx.x * 256 + threadIdx.x;
    const int stride = gridDim.x * 256;
    for (; g < ngroups; g += stride) {
        const int* src = wq + (size_t)g * 8;
        i32x4 v0 = *(const i32x4*)(src);
        i32x4 v1 = *(const i32x4*)(src + 4);
        s16x8 o;
        o[0] = (short)i32_to_bf16_exact(v0[0]);
        o[1] = (short)i32_to_bf16_exact(v0[1]);
        o[2] = (short)i32_to_bf16_exact(v0[2]);
        o[3] = (short)i32_to_bf16_exact(v0[3]);
        o[4] = (short)i32_to_bf16_exact(v1[0]);
        o[5] = (short)i32_to_bf16_exact(v1[1]);
        o[6] = (short)i32_to_bf16_exact(v1[2]);
        o[7] = (short)i32_to_bf16_exact(v1[3]);
        *(s16x8*)(wb + (size_t)g * 8) = o;
    }
}

__global__ __launch_bounds__(256) void convert_x_kernel(
    const float* __restrict__ x, unsigned short* __restrict__ xb) {
    const int ngroups = (Md / 8) * Kd;      // 524,288 groups of 8
    int g = blockIdx.x * 256 + threadIdx.x;
    const int stride = gridDim.x * 256;
    for (; g < ngroups; g += stride) {
        const float* src = x + (size_t)g * 8;
        f32x4 v0 = *(const f32x4*)(src);
        f32x4 v1 = *(const f32x4*)(src + 4);
        s16x8 o;
        o[0] = (short)f32_to_bf16_rne(v0[0]);
        o[1] = (short)f32_to_bf16_rne(v0[1]);
        o[2] = (short)f32_to_bf16_rne(v0[2]);
        o[3] = (short)f32_to_bf16_rne(v0[3]);
        o[4] = (short)f32_to_bf16_rne(v1[0]);
        o[5] = (short)f32_to_bf16_rne(v1[1]);
        o[6] = (short)f32_to_bf16_rne(v1[2]);
        o[7] = (short)f32_to_bf16_rne(v1[3]);
        *(s16x8*)(xb + (size_t)g * 8) = o;
    }
}

// ---------- GEMM: C[m,n] = scale[n] * sum_k A[m,k]*B[n,k] + bias[n] ----------
// A: [M][K] bf16 (row-major), Bw: [N][K] bf16 (row-major, i.e. B^T layout)

__global__ __launch_bounds__(256) void gemm_bt_kernel(
    const unsigned short* __restrict__ A,
    const unsigned short* __restrict__ Bw,
    const float* __restrict__ scale,
    const float* __restrict__ bias,
    float* __restrict__ C) {

    constexpr int NMT = Md / BM;             // 8 m-tiles
    constexpr int NWG = NMT * (Nd / BN);     // 1024 workgroups
    constexpr int CPX = NWG / 8;             // 128 per XCD

    // chunked XCD swizzle (bijective: NWG % 8 == 0), m-fastest work order so
    // the 8 M-tile blocks sharing one B-panel land on the same XCD's L2.
    const int orig = blockIdx.x;
    const int work = (orig & 7) * CPX + (orig >> 3);
    const int mtile = work & (NMT - 1);
    const int ntile = work / NMT;
    const int gm0 = mtile * BM;
    const int gn0 = ntile * BN;

    const int tid  = threadIdx.x;
    const int lane = tid & 63;
    const int wave = tid >> 6;
    const int wr   = wave >> 1;              // 0..1 (m half)
    const int wc   = wave & 1;               // 0..1 (n half)
    const int lr   = lane & 15;              // fragment row
    const int lk   = (lane >> 4) << 3;       // fragment k-offset 0/8/16/24

    __shared__ __align__(16) unsigned short sA[BM][BK];
    __shared__ __align__(16) unsigned short sB[BN][BK];

    f32x4 acc[4][4];
    #pragma unroll
    for (int i = 0; i < 4; ++i)
        #pragma unroll
        for (int j = 0; j < 4; ++j) {
            f32x4 z = {0.f, 0.f, 0.f, 0.f};
            acc[i][j] = z;
        }

    // staging geometry: 256 threads x 16B; wave w covers rows [i*32+w*8, +8)
    const int srow = (wave << 3) + (lane >> 3);   // 0..31
    const int scol = (lane & 7) << 3;             // 0..56 (bf16 elements)

    for (int kt = 0; kt < Kd / BK; ++kt) {
        const int k0 = kt * BK;
        #pragma unroll
        for (int i = 0; i < 4; ++i) {
            gload_lds16(A  + (size_t)(gm0 + i * 32 + srow) * Kd + k0 + scol,
                        &sA[i * 32 + (wave << 3)][0]);
            gload_lds16(Bw + (size_t)(gn0 + i * 32 + srow) * Kd + k0 + scol,
                        &sB[i * 32 + (wave << 3)][0]);
        }
        __syncthreads();   // drains vmcnt before compute (m97 structure)

        #pragma unroll
        for (int kk = 0; kk < 2; ++kk) {
            s16x8 af[4], bfr[4];
            #pragma unroll
            for (int mi = 0; mi < 4; ++mi)
                af[mi] = *(const s16x8*)&sA[(wr << 6) + (mi << 4) + lr][(kk << 5) + lk];
            #pragma unroll
            for (int ni = 0; ni < 4; ++ni)
                bfr[ni] = *(const s16x8*)&sB[(wc << 6) + (ni << 4) + lr][(kk << 5) + lk];
            #pragma unroll
            for (int mi = 0; mi < 4; ++mi)
                #pragma unroll
                for (int ni = 0; ni < 4; ++ni)
                    acc[mi][ni] = __builtin_amdgcn_mfma_f32_16x16x32_bf16(
                        af[mi], bfr[ni], acc[mi][ni], 0, 0, 0);
        }
        __syncthreads();   // before next stage overwrites LDS
    }

    // epilogue: C = scale[n]*acc + bias[n]
    // C/D layout (m89/m91 verified): col = lane&15, row = (lane>>4)*4 + reg
    #pragma unroll
    for (int ni = 0; ni < 4; ++ni) {
        const int gn = gn0 + (wc << 6) + (ni << 4) + lr;
        const float sc = scale[gn];
        const float bi = bias[gn];
        #pragma unroll
        for (int mi = 0; mi < 4; ++mi) {
            const int gm = gm0 + (wr << 6) + (mi << 4) + ((lane >> 4) << 2);
            #pragma unroll
            for (int r = 0; r < 4; ++r) {
                C[(size_t)(gm + r) * Nd + gn] = sc * acc[mi][ni][r] + bi;
            }
        }
    }
}

// ---------- fallback (ws too small): slow but correct ----------

__global__ __launch_bounds__(256) void naive_kernel(
    const float* __restrict__ x, const int* __restrict__ wq,
    const float* __restrict__ scale, const float* __restrict__ bias,
    float* __restrict__ out) {
    const int n = blockIdx.x * 256 + threadIdx.x;
    const int m = blockIdx.y;
    if (n >= Nd) return;
    const float* xr = x + (size_t)m * Kd;
    const int*   wr = wq + (size_t)n * Kd;
    float s = 0.f;
    for (int k = 0; k < Kd; ++k) s += xr[k] * (float)wr[k];
    out[(size_t)m * Nd + n] = s * scale[n] + bias[n];
}

// ---------- launch ----------

extern "C" void kernel_launch(void* const* d_in, const int* in_sizes, int n_in,
                              void* d_out, int out_size, void* d_ws, size_t ws_size,
                              hipStream_t stream) {
    const float* x     = (const float*)d_in[0];
    const int*   wq    = (const int*)d_in[1];
    const float* scale = (const float*)d_in[2];
    const float* bias  = (const float*)d_in[3];
    float* out = (float*)d_out;

    const size_t w_bytes = (size_t)Nd * Kd * sizeof(unsigned short);  // 128 MiB
    const size_t x_bytes = (size_t)Md * Kd * sizeof(unsigned short);  //   8 MiB
    if (ws_size >= w_bytes + x_bytes && d_ws != nullptr) {
        unsigned short* wb = (unsigned short*)d_ws;
        unsigned short* xb = wb + (size_t)Nd * Kd;
        convert_w_kernel<<<4096, 256, 0, stream>>>(wq, wb);
        convert_x_kernel<<<2048, 256, 0, stream>>>(x, xb);
        constexpr int NWG = (Md / BM) * (Nd / BN);  // 1024
        gemm_bt_kernel<<<NWG, 256, 0, stream>>>(xb, wb, scale, bias, out);
    } else {
        dim3 grid(Nd / 256, Md);
        naive_kernel<<<grid, 256, 0, stream>>>(x, wq, scale, bias, out);
    }
}

// Round 2
// 211.018 us; speedup vs baseline: 1.4254x; 1.4254x over previous
//
#include <hip/hip_runtime.h>
#include <hip/hip_bf16.h>

typedef __attribute__((ext_vector_type(4))) float  f32x4;
typedef __attribute__((ext_vector_type(4))) int    i32x4;
typedef __attribute__((ext_vector_type(8))) short  s16x8;

static constexpr int Kd = 4096, Nd = 16384, Md = 1024;
static constexpr int BK = 64;
static constexpr int NT = Kd / BK;   // 64 K-tiles

// ---------- helpers ----------

__device__ __forceinline__ unsigned short f32_to_bf16_rne(float f) {
    unsigned u = __float_as_uint(f);
    unsigned r = u + 0x7FFFu + ((u >> 16) & 1u);
    return (unsigned short)(r >> 16);
}

__device__ __forceinline__ unsigned short i32_to_bf16_exact(int v) {
    return (unsigned short)(__float_as_uint((float)v) >> 16);
}

__device__ __forceinline__ void gload16(const unsigned short* g, unsigned short* l) {
    __builtin_amdgcn_global_load_lds(
        (const __attribute__((address_space(1))) void*)g,
        (__attribute__((address_space(3))) void*)l, 16, 0, 0);
}

// ---------- conversion kernels (unchanged, ~BW-bound) ----------

__global__ __launch_bounds__(256) void convert_w_kernel(
    const int* __restrict__ wq, unsigned short* __restrict__ wb) {
    const int ngroups = (Nd / 8) * Kd;
    int g = blockIdx.x * 256 + threadIdx.x;
    const int stride = gridDim.x * 256;
    for (; g < ngroups; g += stride) {
        const int* src = wq + (size_t)g * 8;
        i32x4 v0 = *(const i32x4*)(src);
        i32x4 v1 = *(const i32x4*)(src + 4);
        s16x8 o;
        o[0] = (short)i32_to_bf16_exact(v0[0]);
        o[1] = (short)i32_to_bf16_exact(v0[1]);
        o[2] = (short)i32_to_bf16_exact(v0[2]);
        o[3] = (short)i32_to_bf16_exact(v0[3]);
        o[4] = (short)i32_to_bf16_exact(v1[0]);
        o[5] = (short)i32_to_bf16_exact(v1[1]);
        o[6] = (short)i32_to_bf16_exact(v1[2]);
        o[7] = (short)i32_to_bf16_exact(v1[3]);
        *(s16x8*)(wb + (size_t)g * 8) = o;
    }
}

__global__ __launch_bounds__(256) void convert_x_kernel(
    const float* __restrict__ x, unsigned short* __restrict__ xb) {
    const int ngroups = (Md / 8) * Kd;
    int g = blockIdx.x * 256 + threadIdx.x;
    const int stride = gridDim.x * 256;
    for (; g < ngroups; g += stride) {
        const float* src = x + (size_t)g * 8;
        f32x4 v0 = *(const f32x4*)(src);
        f32x4 v1 = *(const f32x4*)(src + 4);
        s16x8 o;
        o[0] = (short)f32_to_bf16_rne(v0[0]);
        o[1] = (short)f32_to_bf16_rne(v0[1]);
        o[2] = (short)f32_to_bf16_rne(v0[2]);
        o[3] = (short)f32_to_bf16_rne(v0[3]);
        o[4] = (short)f32_to_bf16_rne(v1[0]);
        o[5] = (short)f32_to_bf16_rne(v1[1]);
        o[6] = (short)f32_to_bf16_rne(v1[2]);
        o[7] = (short)f32_to_bf16_rne(v1[3]);
        *(s16x8*)(xb + (size_t)g * 8) = o;
    }
}

// ---------- 256x256 8-phase GEMM ----------
// C[m,n] = scale[n] * sum_k A[m,k]*B[n,k] + bias[n]
// A: [M][K] bf16, Bw: [N][K] bf16 (B^T layout).
// 8 waves = 2M x 4N; per-wave output 128x64; BK=64; LDS 128 KiB, 2 slots.
// Regions: A_lo = tile rows with bit6==0 (per-wave m-half h=0), A_hi = bit6==1;
//          B_lo = tile rows with bit5==0 (per-wave n-half j=0), B_hi.
// Phase (h,j) order per K-tile: (0,0),(0,1),(1,0),(1,1).
// Stage schedule per group t: P1 A_hi(t+1), P2 B_hi(t+1) [other slot];
//   P3 A_lo(t+2), P4 B_lo(t+2) [same slot, after their last-read barrier].
// vmcnt(4) once per K-tile at P4 before the barrier (2 half-tiles in flight).
// LDS XOR-swizzle: col_byte ^= (row&7)<<4; inverse folded into gload source.

#define BARRIER() asm volatile("s_barrier" ::: "memory")

#define STAGE_A(slot, h, kt) do {                                              \
    unsigned short* lb_ = &LDS[slot][0][h][w * 8][0];                          \
    gload16(Ab + (aRow0 + (h) * 64) * (size_t)Kd + (kt) * BK + gcol, lb_);     \
    gload16(Ab + (aRow0 + (h) * 64 + 128) * (size_t)Kd + (kt) * BK + gcol,     \
            lb_ + 64 * 64);                                                    \
} while (0)

#define STAGE_B(slot, j, kt) do {                                              \
    unsigned short* lb_ = &LDS[slot][1][j][w * 8][0];                          \
    gload16(Bw + (bRow0 + (j) * 32) * (size_t)Kd + (kt) * BK + gcol, lb_);     \
    gload16(Bw + (bRow0 + (j) * 32 + 128) * (size_t)Kd + (kt) * BK + gcol,     \
            lb_ + 64 * 64);                                                    \
} while (0)

#define PHASE(slot, h, j, STAGE_STMT, WAIT_STMT) do {                          \
    s16x8 af[4][2], bfr[2][2];                                                 \
    const char* lA_ = (const char*)&LDS[slot][0][h][0][0];                     \
    const char* lB_ = (const char*)&LDS[slot][1][j][0][0];                     \
    _Pragma("unroll")                                                          \
    for (int mi = 0; mi < 4; ++mi)                                             \
        _Pragma("unroll")                                                      \
        for (int kk = 0; kk < 2; ++kk) {                                       \
            const int row_ = wm * 64 + mi * 16 + lr;                           \
            const int col_ = (l4 * 16 + kk * 64) ^ xorv;                       \
            af[mi][kk] = *(const s16x8*)(lA_ + row_ * 128 + col_);             \
        }                                                                      \
    _Pragma("unroll")                                                          \
    for (int ni = 0; ni < 2; ++ni)                                             \
        _Pragma("unroll")                                                      \
        for (int kk = 0; kk < 2; ++kk) {                                       \
            const int row_ = wn * 32 + ni * 16 + lr;                           \
            const int col_ = (l4 * 16 + kk * 64) ^ xorv;                       \
            bfr[ni][kk] = *(const s16x8*)(lB_ + row_ * 128 + col_);            \
        }                                                                      \
    STAGE_STMT;                                                                \
    WAIT_STMT;                                                                 \
    BARRIER();                                                                 \
    asm volatile("s_waitcnt lgkmcnt(0)");                                      \
    __builtin_amdgcn_sched_barrier(0);                                         \
    __builtin_amdgcn_s_setprio(1);                                             \
    _Pragma("unroll")                                                          \
    for (int mi = 0; mi < 4; ++mi)                                             \
        _Pragma("unroll")                                                      \
        for (int ni = 0; ni < 2; ++ni)                                         \
            _Pragma("unroll")                                                  \
            for (int kk = 0; kk < 2; ++kk)                                     \
                acc[(h) * 4 + mi][(j) * 2 + ni] =                              \
                    __builtin_amdgcn_mfma_f32_16x16x32_bf16(                   \
                        af[mi][kk], bfr[ni][kk],                               \
                        acc[(h) * 4 + mi][(j) * 2 + ni], 0, 0, 0);             \
    __builtin_amdgcn_s_setprio(0);                                             \
    BARRIER();                                                                 \
} while (0)

#define VMCNT_P4(t)                                                            \
    do {                                                                       \
        if ((t) + 2 < NT) asm volatile("s_waitcnt vmcnt(4)" ::: "memory");     \
        else              asm volatile("s_waitcnt vmcnt(0)" ::: "memory");     \
    } while (0)

__global__ __launch_bounds__(512, 2) void gemm8_kernel(
    const unsigned short* __restrict__ Ab,
    const unsigned short* __restrict__ Bw,
    const float* __restrict__ scale,
    const float* __restrict__ bias,
    float* __restrict__ C) {

    __shared__ __align__(16) unsigned short LDS[2][2][2][128][64];  // 128 KiB

    const int tid = threadIdx.x;
    const int l   = tid & 63;
    const int w   = tid >> 6;          // wave 0..7
    const int wm  = w >> 2;            // 0..1
    const int wn  = w & 3;             // 0..3
    const int lr  = l & 15;
    const int l4  = l >> 4;            // 0..3
    const int xorv = (lr & 7) << 4;

    // bijective XCD swizzle (256 wg, 32/XCD), m-fastest work order
    const int orig = blockIdx.x;
    const int work = (orig & 7) * 32 + (orig >> 3);
    const int gm0 = (work & 3) * 256;
    const int gn0 = (work >> 2) * 256;

    // staging source geometry (inverse of read-side XOR swizzle)
    const int g_log = (l & 7) ^ ((l >> 3) & 7);
    const int gcol  = g_log * 8;
    const size_t aRow0 = (size_t)(gm0 + w * 8 + (l >> 3));
    const size_t bRow0 = (size_t)(gn0 + (w >> 2) * 64 + (w & 3) * 8 + (l >> 3));

    f32x4 acc[8][4];
    #pragma unroll
    for (int i = 0; i < 8; ++i)
        #pragma unroll
        for (int j = 0; j < 4; ++j) {
            f32x4 z = {0.f, 0.f, 0.f, 0.f};
            acc[i][j] = z;
        }

    // prologue: tile0 complete + tile1 lo-regions
    STAGE_A(0, 0, 0); STAGE_B(0, 0, 0);
    STAGE_A(0, 1, 0); STAGE_B(0, 1, 0);
    STAGE_A(1, 0, 1); STAGE_B(1, 0, 1);
    asm volatile("s_waitcnt vmcnt(4)" ::: "memory");
    BARRIER();

    #pragma unroll 1
    for (int tt = 0; tt < NT / 2; ++tt) {
        {   // K-tile t = 2*tt, slot 0
            const int t = 2 * tt;
            PHASE(0, 0, 0, { if (t + 1 < NT) STAGE_A(1, 1, t + 1); }, );
            PHASE(0, 0, 1, { if (t + 1 < NT) STAGE_B(1, 1, t + 1); }, );
            PHASE(0, 1, 0, { if (t + 2 < NT) STAGE_A(0, 0, t + 2); }, );
            PHASE(0, 1, 1, { if (t + 2 < NT) STAGE_B(0, 0, t + 2); }, VMCNT_P4(t));
        }
        {   // K-tile t = 2*tt+1, slot 1
            const int t = 2 * tt + 1;
            PHASE(1, 0, 0, { if (t + 1 < NT) STAGE_A(0, 1, t + 1); }, );
            PHASE(1, 0, 1, { if (t + 1 < NT) STAGE_B(0, 1, t + 1); }, );
            PHASE(1, 1, 0, { if (t + 2 < NT) STAGE_A(1, 0, t + 2); }, );
            PHASE(1, 1, 1, { if (t + 2 < NT) STAGE_B(1, 0, t + 2); }, VMCNT_P4(t));
        }
    }

    // epilogue: C = scale[n]*acc + bias[n]
    // C/D layout: col = lane&15 (n), row = (lane>>4)*4 + reg (m)
    #pragma unroll
    for (int bj = 0; bj < 4; ++bj) {
        const int gn = gn0 + wn * 64 + bj * 16 + lr;
        const float sc = scale[gn];
        const float bi = bias[gn];
        #pragma unroll
        for (int ai = 0; ai < 8; ++ai) {
            const int gm = gm0 + wm * 128 + ai * 16 + l4 * 4;
            #pragma unroll
            for (int r = 0; r < 4; ++r)
                C[(size_t)(gm + r) * Nd + gn] = sc * acc[ai][bj][r] + bi;
        }
    }
}

// ---------- fallback (ws too small): slow but correct ----------

__global__ __launch_bounds__(256) void naive_kernel(
    const float* __restrict__ x, const int* __restrict__ wq,
    const float* __restrict__ scale, const float* __restrict__ bias,
    float* __restrict__ out) {
    const int n = blockIdx.x * 256 + threadIdx.x;
    const int m = blockIdx.y;
    if (n >= Nd) return;
    const float* xr = x + (size_t)m * Kd;
    const int*   wr = wq + (size_t)n * Kd;
    float s = 0.f;
    for (int k = 0; k < Kd; ++k) s += xr[k] * (float)wr[k];
    out[(size_t)m * Nd + n] = s * scale[n] + bias[n];
}

// ---------- launch ----------

extern "C" void kernel_launch(void* const* d_in, const int* in_sizes, int n_in,
                              void* d_out, int out_size, void* d_ws, size_t ws_size,
                              hipStream_t stream) {
    const float* x     = (const float*)d_in[0];
    const int*   wq    = (const int*)d_in[1];
    const float* scale = (const float*)d_in[2];
    const float* bias  = (const float*)d_in[3];
    float* out = (float*)d_out;

    const size_t w_bytes = (size_t)Nd * Kd * sizeof(unsigned short);
    const size_t x_bytes = (size_t)Md * Kd * sizeof(unsigned short);
    if (ws_size >= w_bytes + x_bytes && d_ws != nullptr) {
        unsigned short* wb = (unsigned short*)d_ws;
        unsigned short* xb = wb + (size_t)Nd * Kd;
        convert_w_kernel<<<4096, 256, 0, stream>>>(wq, wb);
        convert_x_kernel<<<2048, 256, 0, stream>>>(x, xb);
        gemm8_kernel<<<256, 512, 0, stream>>>(xb, wb, scale, bias, out);
    } else {
        dim3 grid(Nd / 256, Md);
        naive_kernel<<<grid, 256, 0, stream>>>(x, wq, scale, bias, out);
    }
}

// Round 3
// 204.239 us; speedup vs baseline: 1.4727x; 1.0332x over previous
//
#include <hip/hip_runtime.h>
#include <hip/hip_bf16.h>

typedef __attribute__((ext_vector_type(4))) float  f32x4;
typedef __attribute__((ext_vector_type(4))) int    i32x4;
typedef __attribute__((ext_vector_type(8))) short  s16x8;

static constexpr int Kd = 4096, Nd = 16384, Md = 1024;
static constexpr int BK = 64;
static constexpr int NT = Kd / BK;   // 64 K-tiles

// ---------- helpers ----------

__device__ __forceinline__ unsigned short f32_to_bf16_rne(float f) {
    unsigned u = __float_as_uint(f);
    unsigned r = u + 0x7FFFu + ((u >> 16) & 1u);
    return (unsigned short)(r >> 16);
}

__device__ __forceinline__ unsigned short i32_to_bf16_exact(int v) {
    return (unsigned short)(__float_as_uint((float)v) >> 16);
}

__device__ __forceinline__ void gload16(const unsigned short* g, unsigned short* l) {
    __builtin_amdgcn_global_load_lds(
        (const __attribute__((address_space(1))) void*)g,
        (__attribute__((address_space(3))) void*)l, 16, 0, 0);
}

// ---------- conversion kernels (near BW floor, unchanged) ----------

__global__ __launch_bounds__(256) void convert_w_kernel(
    const int* __restrict__ wq, unsigned short* __restrict__ wb) {
    const int ngroups = (Nd / 8) * Kd;
    int g = blockIdx.x * 256 + threadIdx.x;
    const int stride = gridDim.x * 256;
    for (; g < ngroups; g += stride) {
        const int* src = wq + (size_t)g * 8;
        i32x4 v0 = *(const i32x4*)(src);
        i32x4 v1 = *(const i32x4*)(src + 4);
        s16x8 o;
        o[0] = (short)i32_to_bf16_exact(v0[0]);
        o[1] = (short)i32_to_bf16_exact(v0[1]);
        o[2] = (short)i32_to_bf16_exact(v0[2]);
        o[3] = (short)i32_to_bf16_exact(v0[3]);
        o[4] = (short)i32_to_bf16_exact(v1[0]);
        o[5] = (short)i32_to_bf16_exact(v1[1]);
        o[6] = (short)i32_to_bf16_exact(v1[2]);
        o[7] = (short)i32_to_bf16_exact(v1[3]);
        *(s16x8*)(wb + (size_t)g * 8) = o;
    }
}

__global__ __launch_bounds__(256) void convert_x_kernel(
    const float* __restrict__ x, unsigned short* __restrict__ xb) {
    const int ngroups = (Md / 8) * Kd;
    int g = blockIdx.x * 256 + threadIdx.x;
    const int stride = gridDim.x * 256;
    for (; g < ngroups; g += stride) {
        const float* src = x + (size_t)g * 8;
        f32x4 v0 = *(const f32x4*)(src);
        f32x4 v1 = *(const f32x4*)(src + 4);
        s16x8 o;
        o[0] = (short)f32_to_bf16_rne(v0[0]);
        o[1] = (short)f32_to_bf16_rne(v0[1]);
        o[2] = (short)f32_to_bf16_rne(v0[2]);
        o[3] = (short)f32_to_bf16_rne(v0[3]);
        o[4] = (short)f32_to_bf16_rne(v1[0]);
        o[5] = (short)f32_to_bf16_rne(v1[1]);
        o[6] = (short)f32_to_bf16_rne(v1[2]);
        o[7] = (short)f32_to_bf16_rne(v1[3]);
        *(s16x8*)(xb + (size_t)g * 8) = o;
    }
}

// ---------- 256x256 8-phase GEMM, register-cached fragments ----------
// C[m,n] = scale[n] * sum_k A[m,k]*B[n,k] + bias[n]
// 8 waves = 2M x 4N; per-wave 128x64 out; BK=64; LDS 128 KiB, 2 slots.
// Per K-tile, 4 phases (C-quadrants). Fragments read from LDS ONCE and
// register-cached across the two phases that consume them:
//   P1 (0,0): read A0(8 b128)+B0(4); P2 (0,1): read B1(4);
//   P3 (1,0): read A1(8);            P4 (1,1): no reads.
// Stage schedule per tile t: P1 A_hi(t+1), P2 B_hi(t+1) [other slot];
//   P3 A_lo(t+2), P4 B_lo(t+2) [same slot]. vmcnt(4) once per tile at P4.
// All regions of tile t are load-complete before tile t's first phase
// (vmcnt discipline), so early reads are safe; overwrites of each region
// issue >= 2 barriers after its last LDS read.
// LDS XOR-swizzle: col_byte ^= (row&7)<<4; inverse folded into gload source.

#define BARRIER() asm volatile("s_barrier" ::: "memory")

#define LGKM0_FENCE() do {                                                     \
    asm volatile("s_waitcnt lgkmcnt(0)");                                      \
    __builtin_amdgcn_sched_barrier(0);                                         \
} while (0)

#define STAGE_A(slot, h, kt) do {                                              \
    unsigned short* lb_ = &LDS[slot][0][h][w * 8][0];                          \
    gload16(Ab + (aRow0 + (h) * 64) * (size_t)Kd + (kt) * BK + gcol, lb_);     \
    gload16(Ab + (aRow0 + (h) * 64 + 128) * (size_t)Kd + (kt) * BK + gcol,     \
            lb_ + 64 * 64);                                                    \
} while (0)

#define STAGE_B(slot, j, kt) do {                                              \
    unsigned short* lb_ = &LDS[slot][1][j][w * 8][0];                          \
    gload16(Bw + (bRow0 + (j) * 32) * (size_t)Kd + (kt) * BK + gcol, lb_);     \
    gload16(Bw + (bRow0 + (j) * 32 + 128) * (size_t)Kd + (kt) * BK + gcol,     \
            lb_ + 64 * 64);                                                    \
} while (0)

#define READ_A(dst, slot, h) do {                                              \
    const char* lA_ = (const char*)&LDS[slot][0][h][0][0];                     \
    _Pragma("unroll")                                                          \
    for (int mi = 0; mi < 4; ++mi)                                             \
        _Pragma("unroll")                                                      \
        for (int kk = 0; kk < 2; ++kk) {                                       \
            const int row_ = wm * 64 + mi * 16 + lr;                           \
            const int col_ = (l4 * 16 + kk * 64) ^ xorv;                       \
            dst[mi][kk] = *(const s16x8*)(lA_ + row_ * 128 + col_);            \
        }                                                                      \
} while (0)

#define READ_B(dst, slot, j) do {                                              \
    const char* lB_ = (const char*)&LDS[slot][1][j][0][0];                     \
    _Pragma("unroll")                                                          \
    for (int ni = 0; ni < 2; ++ni)                                             \
        _Pragma("unroll")                                                      \
        for (int kk = 0; kk < 2; ++kk) {                                       \
            const int row_ = wn * 32 + ni * 16 + lr;                           \
            const int col_ = (l4 * 16 + kk * 64) ^ xorv;                       \
            dst[ni][kk] = *(const s16x8*)(lB_ + row_ * 128 + col_);            \
        }                                                                      \
} while (0)

#define MFMA_QUAD(h, j, AF, BF) do {                                           \
    __builtin_amdgcn_s_setprio(1);                                             \
    _Pragma("unroll")                                                          \
    for (int mi = 0; mi < 4; ++mi)                                             \
        _Pragma("unroll")                                                      \
        for (int ni = 0; ni < 2; ++ni)                                         \
            _Pragma("unroll")                                                  \
            for (int kk = 0; kk < 2; ++kk)                                     \
                acc[(h) * 4 + mi][(j) * 2 + ni] =                              \
                    __builtin_amdgcn_mfma_f32_16x16x32_bf16(                   \
                        AF[mi][kk], BF[ni][kk],                                \
                        acc[(h) * 4 + mi][(j) * 2 + ni], 0, 0, 0);             \
    __builtin_amdgcn_s_setprio(0);                                             \
} while (0)

#define VMCNT_P4(t)                                                            \
    do {                                                                       \
        if ((t) + 2 < NT) asm volatile("s_waitcnt vmcnt(4)" ::: "memory");     \
        else              asm volatile("s_waitcnt vmcnt(0)" ::: "memory");     \
    } while (0)

// one K-tile = 4 phases; slot = tile parity, oslot = other slot
#define TILE(slot, oslot, t) do {                                              \
    s16x8 afA[4][2], afB[4][2], bfA[2][2], bfB[2][2];                          \
    /* P1: quadrant (0,0) */                                                   \
    READ_A(afA, slot, 0);                                                      \
    READ_B(bfA, slot, 0);                                                      \
    if ((t) + 1 < NT) STAGE_A(oslot, 1, (t) + 1);                              \
    BARRIER(); LGKM0_FENCE();                                                  \
    MFMA_QUAD(0, 0, afA, bfA);                                                 \
    BARRIER();                                                                 \
    /* P2: quadrant (0,1) */                                                   \
    READ_B(bfB, slot, 1);                                                      \
    if ((t) + 1 < NT) STAGE_B(oslot, 1, (t) + 1);                              \
    BARRIER(); LGKM0_FENCE();                                                  \
    MFMA_QUAD(0, 1, afA, bfB);                                                 \
    BARRIER();                                                                 \
    /* P3: quadrant (1,0) */                                                   \
    READ_A(afB, slot, 1);                                                      \
    if ((t) + 2 < NT) STAGE_A(slot, 0, (t) + 2);                               \
    BARRIER(); LGKM0_FENCE();                                                  \
    MFMA_QUAD(1, 0, afB, bfA);                                                 \
    BARRIER();                                                                 \
    /* P4: quadrant (1,1) — no LDS reads, frags cached */                      \
    if ((t) + 2 < NT) STAGE_B(slot, 0, (t) + 2);                               \
    VMCNT_P4(t);                                                               \
    BARRIER();                                                                 \
    MFMA_QUAD(1, 1, afB, bfB);                                                 \
    BARRIER();                                                                 \
} while (0)

__global__ __launch_bounds__(512, 2) void gemm8_kernel(
    const unsigned short* __restrict__ Ab,
    const unsigned short* __restrict__ Bw,
    const float* __restrict__ scale,
    const float* __restrict__ bias,
    float* __restrict__ C) {

    __shared__ __align__(16) unsigned short LDS[2][2][2][128][64];  // 128 KiB

    const int tid = threadIdx.x;
    const int l   = tid & 63;
    const int w   = tid >> 6;          // wave 0..7
    const int wm  = w >> 2;            // 0..1
    const int wn  = w & 3;             // 0..3
    const int lr  = l & 15;
    const int l4  = l >> 4;            // 0..3
    const int xorv = (lr & 7) << 4;

    // bijective XCD swizzle (256 wg, 32/XCD), m-fastest work order
    const int orig = blockIdx.x;
    const int work = (orig & 7) * 32 + (orig >> 3);
    const int gm0 = (work & 3) * 256;
    const int gn0 = (work >> 2) * 256;

    // staging source geometry (inverse of read-side XOR swizzle)
    const int g_log = (l & 7) ^ ((l >> 3) & 7);
    const int gcol  = g_log * 8;
    const size_t aRow0 = (size_t)(gm0 + w * 8 + (l >> 3));
    const size_t bRow0 = (size_t)(gn0 + (w >> 2) * 64 + (w & 3) * 8 + (l >> 3));

    f32x4 acc[8][4];
    #pragma unroll
    for (int i = 0; i < 8; ++i)
        #pragma unroll
        for (int j = 0; j < 4; ++j) {
            f32x4 z = {0.f, 0.f, 0.f, 0.f};
            acc[i][j] = z;
        }

    // prologue: tile0 complete + tile1 lo-regions
    STAGE_A(0, 0, 0); STAGE_B(0, 0, 0);
    STAGE_A(0, 1, 0); STAGE_B(0, 1, 0);
    STAGE_A(1, 0, 1); STAGE_B(1, 0, 1);
    asm volatile("s_waitcnt vmcnt(4)" ::: "memory");
    BARRIER();

    #pragma unroll 1
    for (int tt = 0; tt < NT / 2; ++tt) {
        TILE(0, 1, 2 * tt);
        TILE(1, 0, 2 * tt + 1);
    }

    // epilogue: C = scale[n]*acc + bias[n]
    // C/D layout: col = lane&15 (n), row = (lane>>4)*4 + reg (m)
    #pragma unroll
    for (int bj = 0; bj < 4; ++bj) {
        const int gn = gn0 + wn * 64 + bj * 16 + lr;
        const float sc = scale[gn];
        const float bi = bias[gn];
        #pragma unroll
        for (int ai = 0; ai < 8; ++ai) {
            const int gm = gm0 + wm * 128 + ai * 16 + l4 * 4;
            #pragma unroll
            for (int r = 0; r < 4; ++r)
                C[(size_t)(gm + r) * Nd + gn] = sc * acc[ai][bj][r] + bi;
        }
    }
}

// ---------- fallback (ws too small): slow but correct ----------

__global__ __launch_bounds__(256) void naive_kernel(
    const float* __restrict__ x, const int* __restrict__ wq,
    const float* __restrict__ scale, const float* __restrict__ bias,
    float* __restrict__ out) {
    const int n = blockIdx.x * 256 + threadIdx.x;
    const int m = blockIdx.y;
    if (n >= Nd) return;
    const float* xr = x + (size_t)m * Kd;
    const int*   wr = wq + (size_t)n * Kd;
    float s = 0.f;
    for (int k = 0; k < Kd; ++k) s += xr[k] * (float)wr[k];
    out[(size_t)m * Nd + n] = s * scale[n] + bias[n];
}

// ---------- launch ----------

extern "C" void kernel_launch(void* const* d_in, const int* in_sizes, int n_in,
                              void* d_out, int out_size, void* d_ws, size_t ws_size,
                              hipStream_t stream) {
    const float* x     = (const float*)d_in[0];
    const int*   wq    = (const int*)d_in[1];
    const float* scale = (const float*)d_in[2];
    const float* bias  = (const float*)d_in[3];
    float* out = (float*)d_out;

    const size_t w_bytes = (size_t)Nd * Kd * sizeof(unsigned short);
    const size_t x_bytes = (size_t)Md * Kd * sizeof(unsigned short);
    if (ws_size >= w_bytes + x_bytes && d_ws != nullptr) {
        unsigned short* wb = (unsigned short*)d_ws;
        unsigned short* xb = wb + (size_t)Nd * Kd;
        convert_w_kernel<<<4096, 256, 0, stream>>>(wq, wb);
        convert_x_kernel<<<2048, 256, 0, stream>>>(x, xb);
        gemm8_kernel<<<256, 512, 0, stream>>>(xb, wb, scale, bias, out);
    } else {
        dim3 grid(Nd / 256, Md);
        naive_kernel<<<grid, 256, 0, stream>>>(x, wq, scale, bias, out);
    }
}